// Round 11
// baseline (181.746 us; speedup 1.0000x reference)
//
#include <hip/hip_runtime.h>

typedef unsigned int u32;
typedef unsigned short u16;
typedef short s16x8 __attribute__((ext_vector_type(8)));
typedef float f32x4 __attribute__((ext_vector_type(4)));

#define BETA_MIN 0.1f
#define BETA_MAX 20.0f
#define LOG2E 1.4426950408889634f

#define MFMA16(a, b, c) __builtin_amdgcn_mfma_f32_16x16x32_bf16(a, b, c, 0, 0, 0)

__device__ __forceinline__ u16 f2bf(float f) {
    u32 u = __float_as_uint(f);
    u32 r = u + 0x7FFFu + ((u >> 16) & 1u);   // round-to-nearest-even on bf16 boundary
    return (u16)(r >> 16);
}
__device__ __forceinline__ float bf2f(u16 h) {
    return __uint_as_float(((u32)h) << 16);
}
__device__ __forceinline__ f32x4 zero4() {
    f32x4 z = {0.f, 0.f, 0.f, 0.f};
    return z;
}
// pack 2 fp32 -> 2 bf16 (RNE) in one VALU op; transient regs, no CFG
__device__ __forceinline__ u32 cvtpk_bf16(float a, float b) {
    u32 r;
    asm("v_cvt_pk_bf16_f32 %0, %1, %2" : "=v"(r) : "v"(a), "v"(b));
    return r;
}

// async global->LDS 16B DMA: no VGPR round-trip. Dest = wave-uniform base + lane*16
// (LINEAR), so the bank-swizzle is applied on the per-lane GLOBAL source address and
// again on the LDS read address (both-sides-or-neither, same involution).
__device__ __forceinline__ void gload_lds16(const void* g, void* l) {
    __builtin_amdgcn_global_load_lds(
        (__attribute__((address_space(1))) void*)(void*)g,
        (__attribute__((address_space(3))) void*)l, 16, 0, 0);
}

// DPP lane-rotate within 16-lane rows; VALU-latency cross-lane (vs ds_swizzle ~100cyc)
template <int CTRL>
__device__ __forceinline__ float dppf(float x) {
    return __int_as_float(__builtin_amdgcn_update_dpp(
        0, __float_as_int(x), CTRL, 0xF, 0xF, false));
}
// reduce across the 16 contiguous lanes of a DPP row; all lanes get the result
__device__ __forceinline__ float rowmax16(float x) {
    x = fmaxf(x, dppf<0xB1>(x));    // quad_perm [1,0,3,2]  (xor 1)
    x = fmaxf(x, dppf<0x4E>(x));    // quad_perm [2,3,0,1]  (xor 2)
    x = fmaxf(x, dppf<0x124>(x));   // row_ror:4
    x = fmaxf(x, dppf<0x128>(x));   // row_ror:8
    return x;
}
__device__ __forceinline__ float rowsum16(float x) {
    x += dppf<0xB1>(x);
    x += dppf<0x4E>(x);
    x += dppf<0x124>(x);
    x += dppf<0x128>(x);
    return x;
}

// ---------------------------------------------------------------- fused prep kernel
// blocks [0, nconvblk): x -> Qhi/Qlo bf16x2 split + rowc VP-SDE constants
// blocks [nconvblk, ...): train -> Khi/Klo (row-major) + Vt (LDS-transposed) + y2
// rowc a,b are PRE-SCALED by log2e: flash computes scores in exp2 domain so every
// exp is a bare v_exp_f32 (no v_mul). partML m is in log2 units; combine uses exp2f.
__global__ __launch_bounds__(256)
void prep_kernel(const float* __restrict__ x, const float* __restrict__ t,
                 const float* __restrict__ train,
                 u16* __restrict__ Qhi, u16* __restrict__ Qlo, float* __restrict__ rowc,
                 u16* __restrict__ Khi, u16* __restrict__ Klo, u16* __restrict__ Vt,
                 float* __restrict__ y2, int total4, int N, int M, int nconvblk) {
    __shared__ u16 T[128][66];
    if ((int)blockIdx.x < nconvblk) {
        int idx = blockIdx.x * 256 + threadIdx.x;
        if (idx < N) {
            float tv   = t[idx];
            float lm   = -0.25f * tv * tv * (BETA_MAX - BETA_MIN) - 0.5f * tv * BETA_MIN;
            float mean = __expf(lm);
            float e2   = __expf(2.0f * lm);
            float s2   = fmaxf(1.0f - e2, 1e-12f);
            float iv   = 1.0f / s2;
            rowc[idx * 4 + 0] = mean * iv * LOG2E;
            rowc[idx * 4 + 1] = -0.5f * mean * mean * iv * LOG2E;
            rowc[idx * 4 + 2] = iv;
            rowc[idx * 4 + 3] = 0.f;
        }
        if (idx >= total4) return;
        float4 v = ((const float4*)x)[idx];
        float f[4] = {v.x, v.y, v.z, v.w};
        u32 hp[2], lp[2];
        u16 h[4], l[4];
#pragma unroll
        for (int j = 0; j < 4; ++j) {
            h[j] = f2bf(f[j]);
            l[j] = f2bf(f[j] - bf2f(h[j]));
        }
        hp[0] = (u32)h[0] | ((u32)h[1] << 16);
        hp[1] = (u32)h[2] | ((u32)h[3] << 16);
        lp[0] = (u32)l[0] | ((u32)l[1] << 16);
        lp[1] = (u32)l[2] | ((u32)l[3] << 16);
        ((uint2*)Qhi)[idx] = make_uint2(hp[0], hp[1]);
        ((uint2*)Qlo)[idx] = make_uint2(lp[0], lp[1]);
        return;
    }
    // ---- train prep ----
    const int tt = threadIdx.x;
    const int m0 = (blockIdx.x - nconvblk) * 64;
    const int g = tt >> 5, ln = tt & 31;
#pragma unroll
    for (int i = 0; i < 8; ++i) {
        int lr = i * 8 + g;
        int m  = m0 + lr;
        const float* row = train + (size_t)m * 128;
        u16* kh = Khi + (size_t)m * 128;
        u16* kl = Klo + (size_t)m * 128;
        float acc = 0.f;
#pragma unroll
        for (int j = 0; j < 4; ++j) {
            int d = ln + 32 * j;
            float v = row[d];                    // coalesced: lanes 0..31 -> 128B line
            u16 h = f2bf(v);
            u16 l = f2bf(v - bf2f(h));
            T[d][lr] = h;                        // conflict-free transpose write
            kh[d] = h;                           // 32-lane 64B segments
            kl[d] = l;
            acc += v * v;
        }
#pragma unroll
        for (int d = 16; d >= 1; d >>= 1) acc += __shfl_xor(acc, d, 32);
        if (ln == 0) y2[m] = acc;
    }
    __syncthreads();
#pragma unroll
    for (int i = 0; i < 4; ++i) {
        int c = i * 256 + tt;                    // 0..1023
        int d = c >> 3, mo = (c & 7) * 8;
        u32 w0 = *(const u32*)&T[d][mo + 0];
        u32 w1 = *(const u32*)&T[d][mo + 2];
        u32 w2 = *(const u32*)&T[d][mo + 4];
        u32 w3 = *(const u32*)&T[d][mo + 6];
        *(uint4*)(Vt + (size_t)d * M + m0 + mo) = make_uint4(w0, w1, w2, w3);
    }
}

// ---------------------------------------------------------------- flash kernel
// grid = (split, N/128); block = 512 (8 waves, 16 q-rows/wave).
// r6 structure (108us, VGPR 64, no scratch): global_load_lds double-buffer, one
// barrier per tile, both-sides XOR swizzle, XCD-locked chunks (FETCH 14.7MB).
// SPILL LEDGER (do not reintroduce): r1 reg-staging, r2/r3/r7 defer-max branch --
// ANY divergent-CFG or extra live state across the softmax loop (O[8] = 32 f32 live)
// tips hipcc regalloc into scratch (WRITE 33MB -> 0.85/6.6/8.1 GB). Softmax must
// stay BRANCHLESS. r9 branchless VALU cuts (VALUBusy was 50%, top consumer):
//  - exp2-domain scores (a,b pre-scaled by log2e): v_exp without v_mul
//  - v_cvt_pk_bf16_f32 P-pack: 1 op vs 2x ~4-op manual RNE
//  - alpha[4] + single f32x4 O-rescale pass: enables v_pk_mul_f32 (2 f32/op)
// Tripwire: WRITE_SIZE > 40MB => revert to r8.
__global__ __launch_bounds__(512, 4)
void flash_kernel(const u16* __restrict__ Khi, const u16* __restrict__ Klo,
                  const u16* __restrict__ Vt,  const u16* __restrict__ Qhi,
                  const u16* __restrict__ Qlo, const float* __restrict__ rowc,
                  const float* __restrict__ y2, float* __restrict__ partO,
                  float* __restrict__ partML, int N, int M, int mchunk) {
    __shared__ u16 sK[2][2][32][128];  // [buf][hi/lo][row][d] LINEAR (DMA dest)
    __shared__ u16 sV[2][128][32];     // [buf][d][m]          LINEAR (DMA dest)
    __shared__ u16 sP[8][16][40];      // per-wave P tile (C-layout -> A-layout)

    const int tid  = threadIdx.x;
    const int wave = tid >> 6, lane = tid & 63;
    const int l15  = lane & 15, quad = lane >> 4;
    const int chunk = blockIdx.x, qb = blockIdx.y;
    const int q0 = qb * 128 + wave * 16;
    const int m_begin = chunk * mchunk;

    // staging source pointers, per-lane, chunk-XOR pre-swizzled to match the reads
    const int kr = tid >> 4;                    // K row 0..31
    const int kc = (tid & 15) ^ (kr & 7);       // source 16B-chunk (involution)
    const int vd = tid >> 2;                    // V d-row 0..127
    const int vc = (tid & 3) ^ ((vd >> 1) & 3);
    const u16* gKh = Khi + (size_t)(m_begin + kr) * 128 + kc * 8;
    const u16* gKl = Klo + (size_t)(m_begin + kr) * 128 + kc * 8;
    const u16* gV  = Vt  + (size_t)vd * M + m_begin + vc * 8;
    const int wb = wave * 1024;                 // wave-uniform byte offset per plane

    // LDS read byte-offsets (hoisted; same XOR as the staged source)
    int aK[4];
#pragma unroll
    for (int kb = 0; kb < 4; ++kb)
        aK[kb] = l15 * 256 + ((((kb * 4 + quad) ^ (l15 & 7))) << 4);
    const int aV = l15 * 64 + ((quad ^ ((l15 >> 1) & 3)) << 4);

    // Q fragments in registers: A-layout A[m=l15][k=quad*8+j]
    s16x8 qh[4], ql[4];
    {
        int row = q0 + l15;
        const u16* ph = Qhi + (size_t)row * 128;
        const u16* pl = Qlo + (size_t)row * 128;
#pragma unroll
        for (int kb = 0; kb < 4; ++kb) {
            qh[kb] = *(const s16x8*)(ph + kb * 32 + quad * 8);
            ql[kb] = *(const s16x8*)(pl + kb * 32 + quad * 8);
        }
    }
    float av[4], bv[4];
#pragma unroll
    for (int k = 0; k < 4; ++k) {
        int r = q0 + quad * 4 + k;
        av[k] = rowc[r * 4 + 0];
        bv[k] = rowc[r * 4 + 1];
    }

    f32x4 O[8];
#pragma unroll
    for (int db = 0; db < 8; ++db) O[db] = zero4();
    float m_run[4], l_run[4];
#pragma unroll
    for (int k = 0; k < 4; ++k) { m_run[k] = -INFINITY; l_run[k] = 0.f; }

    // stage(buf): 3 async 16B DMAs per thread, zero data VGPRs; advances sources
    auto stage = [&](int buf) {
        gload_lds16(gKh, (char*)&sK[buf][0][0][0] + wb);
        gload_lds16(gKl, (char*)&sK[buf][1][0][0] + wb);
        gload_lds16(gV,  (char*)&sV[buf][0][0]    + wb);
        gKh += 32 * 128; gKl += 32 * 128; gV += 32;
    };

    stage(0);
    __syncthreads();                    // implicit vmcnt(0) drain: tile 0 ready
    int cur = 0;

    for (int mt = 0; mt < mchunk; mt += 32) {
        if (mt + 32 < mchunk) stage(cur ^ 1);   // async: lands by next barrier
        const int m0 = m_begin + mt;
        float y2v0 = y2[m0 + l15];
        float y2v1 = y2[m0 + 16 + l15];

        const char* Kb = (const char*)&sK[cur][0][0][0];
        const char* Vb = (const char*)&sV[cur][0][0];

        // S GEMM: bf16x3
        f32x4 S[2];
        S[0] = zero4(); S[1] = zero4();
        __builtin_amdgcn_s_setprio(1);
#pragma unroll
        for (int kb = 0; kb < 4; ++kb) {
            s16x8 bh0 = *(const s16x8*)(Kb + aK[kb]);           // hi, rows l15
            s16x8 bh1 = *(const s16x8*)(Kb + aK[kb] + 4096);    // hi, rows 16+l15
            s16x8 bl0 = *(const s16x8*)(Kb + aK[kb] + 8192);    // lo, rows l15
            s16x8 bl1 = *(const s16x8*)(Kb + aK[kb] + 12288);   // lo, rows 16+l15
            S[0] = MFMA16(qh[kb], bh0, S[0]);
            S[0] = MFMA16(ql[kb], bh0, S[0]);
            S[0] = MFMA16(qh[kb], bl0, S[0]);
            S[1] = MFMA16(qh[kb], bh1, S[1]);
            S[1] = MFMA16(ql[kb], bh1, S[1]);
            S[1] = MFMA16(qh[kb], bl1, S[1]);
        }
        __builtin_amdgcn_s_setprio(0);

        // online softmax (BRANCHLESS, exp2 domain); C-layout: row q = quad*4+k
        // (16 contiguous lanes = one DPP row). alpha kept as 4 named scalars for
        // the single vectorized O-rescale pass below.
        float alpha[4];
#pragma unroll
        for (int k = 0; k < 4; ++k) {
            float s0 = av[k] * S[0][k] + bv[k] * y2v0;
            float s1 = av[k] * S[1][k] + bv[k] * y2v1;
            float rm    = rowmax16(fmaxf(s0, s1));
            float mnew  = fmaxf(m_run[k], rm);
            alpha[k]    = exp2f(m_run[k] - mnew);    // exp2(-inf)=0 on first tile
            float p0 = exp2f(s0 - mnew);
            float p1 = exp2f(s1 - mnew);
            m_run[k] = mnew;
            // deferred row-sum: per-lane partial; alpha is row-uniform so this is exact
            l_run[k] = l_run[k] * alpha[k] + (p0 + p1);
            u32 pk = cvtpk_bf16(p0, p1);
            sP[wave][quad * 4 + k][l15]      = (u16)pk;
            sP[wave][quad * 4 + k][16 + l15] = (u16)(pk >> 16);
        }
        {
            f32x4 alv = {alpha[0], alpha[1], alpha[2], alpha[3]};
#pragma unroll
            for (int db = 0; db < 8; ++db) O[db] *= alv;   // v_pk_mul_f32 candidate
        }
        // same-wave LDS write->read ordering (per-wave sP region; lgkm only --
        // does NOT stall on the outstanding global_load_lds DMAs, which are vmcnt)
        asm volatile("s_waitcnt lgkmcnt(0)" ::: "memory");

        // PV: A = P (A-layout), B = Vt (B[k=m][n=d])
        s16x8 pa = *(const s16x8*)&sP[wave][l15][quad * 8];
        __builtin_amdgcn_s_setprio(1);
#pragma unroll
        for (int db = 0; db < 8; ++db) {
            s16x8 vb = *(const s16x8*)(Vb + db * 1024 + aV);
            O[db] = MFMA16(pa, vb, O[db]);
        }
        __builtin_amdgcn_s_setprio(0);
        __syncthreads();   // drains vmcnt: next tile's DMAs landed; all reads done
        cur ^= 1;
    }

    // epilogue: unnormalized O + (m, l) partials (m in log2 units)
#pragma unroll
    for (int db = 0; db < 8; ++db) {
#pragma unroll
        for (int k = 0; k < 4; ++k) {
            int row = q0 + quad * 4 + k;
            partO[((size_t)chunk * N + row) * 128 + db * 16 + l15] = O[db][k];
        }
    }
#pragma unroll
    for (int k = 0; k < 4; ++k) {
        float lsum = rowsum16(l_run[k]);
        if (l15 == 0) {
            int row = q0 + quad * 4 + k;
            partML[((size_t)chunk * N + row) * 2 + 0] = m_run[k];
            partML[((size_t)chunk * N + row) * 2 + 1] = lsum;
        }
    }
}

// ---------------------------------------------------------------- combine
// partML m is in LOG2 units (flash computes scores in exp2 domain) -> exp2f here.
__global__ void combine_kernel(const float* __restrict__ partO, const float* __restrict__ partML,
                               const float* __restrict__ x, const float* __restrict__ rowc,
                               float* __restrict__ out, int N, int split) {
    int n = blockIdx.x, d = threadIdx.x;
    float Mx = -INFINITY;
    for (int c = 0; c < split; ++c)
        Mx = fmaxf(Mx, partML[((size_t)c * N + n) * 2]);
    float L = 0.f, acc = 0.f;
    for (int c = 0; c < split; ++c) {
        float w = exp2f(partML[((size_t)c * N + n) * 2] - Mx);
        L   += w * partML[((size_t)c * N + n) * 2 + 1];
        acc += w * partO[((size_t)c * N + n) * 128 + d];
    }
    float evals = acc / L;
    if (evals != evals) evals = 0.f;   // match reference's isnan guard
    float iv = rowc[n * 4 + 2];
    out[(size_t)n * 128 + d] = (evals - x[(size_t)n * 128 + d]) * iv;
}

// ---------------------------------------------------------------- launch
extern "C" void kernel_launch(void* const* d_in, const int* in_sizes, int n_in,
                              void* d_out, int out_size, void* d_ws, size_t ws_size,
                              hipStream_t stream) {
    const float* x     = (const float*)d_in[0];
    const float* t     = (const float*)d_in[1];
    const float* train = (const float*)d_in[2];
    float* out = (float*)d_out;

    const int N = in_sizes[1];            // 4096
    const int D = 128;
    const int M = in_sizes[2] / D;        // 16384

    char* ws = (char*)d_ws;
    size_t off = 0;
    auto alloc = [&](size_t bytes) -> void* {
        void* p = ws + off;
        off = (off + bytes + 255) & ~(size_t)255;
        return p;
    };
    u16* Khi   = (u16*)alloc((size_t)M * D * 2);
    u16* Klo   = (u16*)alloc((size_t)M * D * 2);
    u16* Vt    = (u16*)alloc((size_t)M * D * 2);
    u16* Qhi   = (u16*)alloc((size_t)N * D * 2);
    u16* Qlo   = (u16*)alloc((size_t)N * D * 2);
    float* rowc = (float*)alloc((size_t)N * 16);
    float* y2   = (float*)alloc((size_t)M * 4);
    size_t base = off;
    size_t per  = (size_t)N * D * 4 + (size_t)N * 8 + 512;   // partO + partML per chunk
    int split = 16;
    while (split > 1 && base + per * split > ws_size) split >>= 1;
    float* partO  = (float*)alloc((size_t)split * N * D * 4);
    float* partML = (float*)alloc((size_t)split * N * 8);

    int nconvblk = (N * D / 4 + 255) / 256;          // 512
    int nblk = nconvblk + M / 64;                    // + 256
    prep_kernel<<<nblk, 256, 0, stream>>>(x, t, train, Qhi, Qlo, rowc,
                                          Khi, Klo, Vt, y2, N * D / 4, N, M, nconvblk);

    int mchunk = M / split;
    dim3 grid(split, N / 128);
    flash_kernel<<<grid, 512, 0, stream>>>(Khi, Klo, Vt, Qhi, Qlo, rowc, y2,
                                           partO, partML, N, M, mchunk);
    combine_kernel<<<N, 128, 0, stream>>>(partO, partML, x, rowc, out, N, split);
}

// Round 14
// 177.475 us; speedup vs baseline: 1.0241x; 1.0241x over previous
//
#include <hip/hip_runtime.h>

typedef unsigned int u32;
typedef unsigned short u16;
typedef short s16x8 __attribute__((ext_vector_type(8)));
typedef float f32x4 __attribute__((ext_vector_type(4)));

#define BETA_MIN 0.1f
#define BETA_MAX 20.0f

#define MFMA16(a, b, c) __builtin_amdgcn_mfma_f32_16x16x32_bf16(a, b, c, 0, 0, 0)

__device__ __forceinline__ u16 f2bf(float f) {
    u32 u = __float_as_uint(f);
    u32 r = u + 0x7FFFu + ((u >> 16) & 1u);   // round-to-nearest-even on bf16 boundary
    return (u16)(r >> 16);
}
__device__ __forceinline__ float bf2f(u16 h) {
    return __uint_as_float(((u32)h) << 16);
}
__device__ __forceinline__ f32x4 zero4() {
    f32x4 z = {0.f, 0.f, 0.f, 0.f};
    return z;
}

// async global->LDS 16B DMA: no VGPR round-trip. Dest = wave-uniform base + lane*16
// (LINEAR), so the bank-swizzle is applied on the per-lane GLOBAL source address and
// again on the LDS read address (both-sides-or-neither, same involution).
__device__ __forceinline__ void gload_lds16(const void* g, void* l) {
    __builtin_amdgcn_global_load_lds(
        (__attribute__((address_space(1))) void*)(void*)g,
        (__attribute__((address_space(3))) void*)l, 16, 0, 0);
}

// DPP lane-rotate within 16-lane rows; VALU-latency cross-lane (vs ds_swizzle ~100cyc)
template <int CTRL>
__device__ __forceinline__ float dppf(float x) {
    return __int_as_float(__builtin_amdgcn_update_dpp(
        0, __float_as_int(x), CTRL, 0xF, 0xF, false));
}
// reduce across the 16 contiguous lanes of a DPP row; all lanes get the result
__device__ __forceinline__ float rowmax16(float x) {
    x = fmaxf(x, dppf<0xB1>(x));    // quad_perm [1,0,3,2]  (xor 1)
    x = fmaxf(x, dppf<0x4E>(x));    // quad_perm [2,3,0,1]  (xor 2)
    x = fmaxf(x, dppf<0x124>(x));   // row_ror:4
    x = fmaxf(x, dppf<0x128>(x));   // row_ror:8
    return x;
}
__device__ __forceinline__ float rowsum16(float x) {
    x += dppf<0xB1>(x);
    x += dppf<0x4E>(x);
    x += dppf<0x124>(x);
    x += dppf<0x128>(x);
    return x;
}

// ---------------------------------------------------------------- fused prep kernel
// blocks [0, nconvblk): x -> Qhi/Qlo bf16x2 split + rowc VP-SDE constants
// blocks [nconvblk, ...): train -> Khi/Klo (row-major) + Vt (LDS-transposed) + y2
__global__ __launch_bounds__(256)
void prep_kernel(const float* __restrict__ x, const float* __restrict__ t,
                 const float* __restrict__ train,
                 u16* __restrict__ Qhi, u16* __restrict__ Qlo, float* __restrict__ rowc,
                 u16* __restrict__ Khi, u16* __restrict__ Klo, u16* __restrict__ Vt,
                 float* __restrict__ y2, int total4, int N, int M, int nconvblk) {
    __shared__ u16 T[128][66];
    if ((int)blockIdx.x < nconvblk) {
        int idx = blockIdx.x * 256 + threadIdx.x;
        if (idx < N) {
            float tv   = t[idx];
            float lm   = -0.25f * tv * tv * (BETA_MAX - BETA_MIN) - 0.5f * tv * BETA_MIN;
            float mean = __expf(lm);
            float e2   = __expf(2.0f * lm);
            float s2   = fmaxf(1.0f - e2, 1e-12f);
            float iv   = 1.0f / s2;
            rowc[idx * 4 + 0] = mean * iv;
            rowc[idx * 4 + 1] = -0.5f * mean * mean * iv;
            rowc[idx * 4 + 2] = iv;
            rowc[idx * 4 + 3] = 0.f;
        }
        if (idx >= total4) return;
        float4 v = ((const float4*)x)[idx];
        float f[4] = {v.x, v.y, v.z, v.w};
        u32 hp[2], lp[2];
        u16 h[4], l[4];
#pragma unroll
        for (int j = 0; j < 4; ++j) {
            h[j] = f2bf(f[j]);
            l[j] = f2bf(f[j] - bf2f(h[j]));
        }
        hp[0] = (u32)h[0] | ((u32)h[1] << 16);
        hp[1] = (u32)h[2] | ((u32)h[3] << 16);
        lp[0] = (u32)l[0] | ((u32)l[1] << 16);
        lp[1] = (u32)l[2] | ((u32)l[3] << 16);
        ((uint2*)Qhi)[idx] = make_uint2(hp[0], hp[1]);
        ((uint2*)Qlo)[idx] = make_uint2(lp[0], lp[1]);
        return;
    }
    // ---- train prep ----
    const int tt = threadIdx.x;
    const int m0 = (blockIdx.x - nconvblk) * 64;
    const int g = tt >> 5, ln = tt & 31;
#pragma unroll
    for (int i = 0; i < 8; ++i) {
        int lr = i * 8 + g;
        int m  = m0 + lr;
        const float* row = train + (size_t)m * 128;
        u16* kh = Khi + (size_t)m * 128;
        u16* kl = Klo + (size_t)m * 128;
        float acc = 0.f;
#pragma unroll
        for (int j = 0; j < 4; ++j) {
            int d = ln + 32 * j;
            float v = row[d];                    // coalesced: lanes 0..31 -> 128B line
            u16 h = f2bf(v);
            u16 l = f2bf(v - bf2f(h));
            T[d][lr] = h;                        // conflict-free transpose write
            kh[d] = h;                           // 32-lane 64B segments
            kl[d] = l;
            acc += v * v;
        }
#pragma unroll
        for (int d = 16; d >= 1; d >>= 1) acc += __shfl_xor(acc, d, 32);
        if (ln == 0) y2[m] = acc;
    }
    __syncthreads();
#pragma unroll
    for (int i = 0; i < 4; ++i) {
        int c = i * 256 + tt;                    // 0..1023
        int d = c >> 3, mo = (c & 7) * 8;
        u32 w0 = *(const u32*)&T[d][mo + 0];
        u32 w1 = *(const u32*)&T[d][mo + 2];
        u32 w2 = *(const u32*)&T[d][mo + 4];
        u32 w3 = *(const u32*)&T[d][mo + 6];
        *(uint4*)(Vt + (size_t)d * M + m0 + mo) = make_uint4(w0, w1, w2, w3);
    }
}

// ---------------------------------------------------------------- flash kernel
// grid = (split, N/128); block = 512 (8 waves, 16 q-rows/wave).
// FINAL VERIFIED FORM (r8: passed absmax 0.5, flash ~108-110us, VGPR 64, no scratch):
// global_load_lds double-buffer, one barrier per tile, both-sides XOR swizzle,
// XCD-locked chunks (FETCH 14.7MB), branchless f2bf softmax.
// SPILL/FRAGILITY LEDGER (r1-r13, do not reintroduce):
//  - reg-staging (r1), defer-max branch (r2/r3/r7): scratch spills 0.85-8.1 GB
//  - libm exp2f (r11): +15% VALU; raw exp2 builtin (r12): WRONG (absmax 2.9e6)
//  - cvtpk+vec-rescale in __expf build (r13): WRONG (absmax 77) -- schedule-fragile
// The softmax below is the only verified-correct codegen: branchless, scalar
// f2bf pack, in-loop scalar O-rescale, __expf.
__global__ __launch_bounds__(512, 4)
void flash_kernel(const u16* __restrict__ Khi, const u16* __restrict__ Klo,
                  const u16* __restrict__ Vt,  const u16* __restrict__ Qhi,
                  const u16* __restrict__ Qlo, const float* __restrict__ rowc,
                  const float* __restrict__ y2, float* __restrict__ partO,
                  float* __restrict__ partML, int N, int M, int mchunk) {
    __shared__ u16 sK[2][2][32][128];  // [buf][hi/lo][row][d] LINEAR (DMA dest)
    __shared__ u16 sV[2][128][32];     // [buf][d][m]          LINEAR (DMA dest)
    __shared__ u16 sP[8][16][40];      // per-wave P tile (C-layout -> A-layout)

    const int tid  = threadIdx.x;
    const int wave = tid >> 6, lane = tid & 63;
    const int l15  = lane & 15, quad = lane >> 4;
    const int chunk = blockIdx.x, qb = blockIdx.y;
    const int q0 = qb * 128 + wave * 16;
    const int m_begin = chunk * mchunk;

    // staging source pointers, per-lane, chunk-XOR pre-swizzled to match the reads
    const int kr = tid >> 4;                    // K row 0..31
    const int kc = (tid & 15) ^ (kr & 7);       // source 16B-chunk (involution)
    const int vd = tid >> 2;                    // V d-row 0..127
    const int vc = (tid & 3) ^ ((vd >> 1) & 3);
    const u16* gKh = Khi + (size_t)(m_begin + kr) * 128 + kc * 8;
    const u16* gKl = Klo + (size_t)(m_begin + kr) * 128 + kc * 8;
    const u16* gV  = Vt  + (size_t)vd * M + m_begin + vc * 8;
    const int wb = wave * 1024;                 // wave-uniform byte offset per plane

    // LDS read byte-offsets (hoisted; same XOR as the staged source)
    int aK[4];
#pragma unroll
    for (int kb = 0; kb < 4; ++kb)
        aK[kb] = l15 * 256 + ((((kb * 4 + quad) ^ (l15 & 7))) << 4);
    const int aV = l15 * 64 + ((quad ^ ((l15 >> 1) & 3)) << 4);

    // Q fragments in registers: A-layout A[m=l15][k=quad*8+j]
    s16x8 qh[4], ql[4];
    {
        int row = q0 + l15;
        const u16* ph = Qhi + (size_t)row * 128;
        const u16* pl = Qlo + (size_t)row * 128;
#pragma unroll
        for (int kb = 0; kb < 4; ++kb) {
            qh[kb] = *(const s16x8*)(ph + kb * 32 + quad * 8);
            ql[kb] = *(const s16x8*)(pl + kb * 32 + quad * 8);
        }
    }
    float av[4], bv[4];
#pragma unroll
    for (int k = 0; k < 4; ++k) {
        int r = q0 + quad * 4 + k;
        av[k] = rowc[r * 4 + 0];
        bv[k] = rowc[r * 4 + 1];
    }

    f32x4 O[8];
#pragma unroll
    for (int db = 0; db < 8; ++db) O[db] = zero4();
    float m_run[4], l_run[4];
#pragma unroll
    for (int k = 0; k < 4; ++k) { m_run[k] = -INFINITY; l_run[k] = 0.f; }

    // stage(buf): 3 async 16B DMAs per thread, zero data VGPRs; advances sources
    auto stage = [&](int buf) {
        gload_lds16(gKh, (char*)&sK[buf][0][0][0] + wb);
        gload_lds16(gKl, (char*)&sK[buf][1][0][0] + wb);
        gload_lds16(gV,  (char*)&sV[buf][0][0]    + wb);
        gKh += 32 * 128; gKl += 32 * 128; gV += 32;
    };

    stage(0);
    __syncthreads();                    // implicit vmcnt(0) drain: tile 0 ready
    int cur = 0;

    for (int mt = 0; mt < mchunk; mt += 32) {
        if (mt + 32 < mchunk) stage(cur ^ 1);   // async: lands by next barrier
        const int m0 = m_begin + mt;
        float y2v0 = y2[m0 + l15];
        float y2v1 = y2[m0 + 16 + l15];

        const char* Kb = (const char*)&sK[cur][0][0][0];
        const char* Vb = (const char*)&sV[cur][0][0];

        // S GEMM: bf16x3
        f32x4 S[2];
        S[0] = zero4(); S[1] = zero4();
        __builtin_amdgcn_s_setprio(1);
#pragma unroll
        for (int kb = 0; kb < 4; ++kb) {
            s16x8 bh0 = *(const s16x8*)(Kb + aK[kb]);           // hi, rows l15
            s16x8 bh1 = *(const s16x8*)(Kb + aK[kb] + 4096);    // hi, rows 16+l15
            s16x8 bl0 = *(const s16x8*)(Kb + aK[kb] + 8192);    // lo, rows l15
            s16x8 bl1 = *(const s16x8*)(Kb + aK[kb] + 12288);   // lo, rows 16+l15
            S[0] = MFMA16(qh[kb], bh0, S[0]);
            S[0] = MFMA16(ql[kb], bh0, S[0]);
            S[0] = MFMA16(qh[kb], bl0, S[0]);
            S[1] = MFMA16(qh[kb], bh1, S[1]);
            S[1] = MFMA16(ql[kb], bh1, S[1]);
            S[1] = MFMA16(qh[kb], bl1, S[1]);
        }
        __builtin_amdgcn_s_setprio(0);

        // online softmax (BRANCHLESS -- see ledger above); C-layout:
        // row q = quad*4+k (16 contiguous lanes = one DPP row)
#pragma unroll
        for (int k = 0; k < 4; ++k) {
            float s0 = av[k] * S[0][k] + bv[k] * y2v0;
            float s1 = av[k] * S[1][k] + bv[k] * y2v1;
            float rm    = rowmax16(fmaxf(s0, s1));
            float mnew  = fmaxf(m_run[k], rm);
            float alpha = __expf(m_run[k] - mnew);   // exp(-inf)=0 on first tile
            float p0 = __expf(s0 - mnew);
            float p1 = __expf(s1 - mnew);
            m_run[k] = mnew;
            // deferred row-sum: per-lane partial; alpha is row-uniform so this is exact
            l_run[k] = l_run[k] * alpha + (p0 + p1);
            sP[wave][quad * 4 + k][l15]      = f2bf(p0);
            sP[wave][quad * 4 + k][16 + l15] = f2bf(p1);
#pragma unroll
            for (int db = 0; db < 8; ++db) O[db][k] *= alpha;
        }
        // same-wave LDS write->read ordering (per-wave sP region; lgkm only --
        // does NOT stall on the outstanding global_load_lds DMAs, which are vmcnt)
        asm volatile("s_waitcnt lgkmcnt(0)" ::: "memory");

        // PV: A = P (A-layout), B = Vt (B[k=m][n=d])
        s16x8 pa = *(const s16x8*)&sP[wave][l15][quad * 8];
        __builtin_amdgcn_s_setprio(1);
#pragma unroll
        for (int db = 0; db < 8; ++db) {
            s16x8 vb = *(const s16x8*)(Vb + db * 1024 + aV);
            O[db] = MFMA16(pa, vb, O[db]);
        }
        __builtin_amdgcn_s_setprio(0);
        __syncthreads();   // drains vmcnt: next tile's DMAs landed; all reads done
        cur ^= 1;
    }

    // epilogue: unnormalized O + (m, l) partials
#pragma unroll
    for (int db = 0; db < 8; ++db) {
#pragma unroll
        for (int k = 0; k < 4; ++k) {
            int row = q0 + quad * 4 + k;
            partO[((size_t)chunk * N + row) * 128 + db * 16 + l15] = O[db][k];
        }
    }
#pragma unroll
    for (int k = 0; k < 4; ++k) {
        float lsum = rowsum16(l_run[k]);
        if (l15 == 0) {
            int row = q0 + quad * 4 + k;
            partML[((size_t)chunk * N + row) * 2 + 0] = m_run[k];
            partML[((size_t)chunk * N + row) * 2 + 1] = lsum;
        }
    }
}

// ---------------------------------------------------------------- combine
__global__ void combine_kernel(const float* __restrict__ partO, const float* __restrict__ partML,
                               const float* __restrict__ x, const float* __restrict__ rowc,
                               float* __restrict__ out, int N, int split) {
    int n = blockIdx.x, d = threadIdx.x;
    float Mx = -INFINITY;
    for (int c = 0; c < split; ++c)
        Mx = fmaxf(Mx, partML[((size_t)c * N + n) * 2]);
    float L = 0.f, acc = 0.f;
    for (int c = 0; c < split; ++c) {
        float w = __expf(partML[((size_t)c * N + n) * 2] - Mx);
        L   += w * partML[((size_t)c * N + n) * 2 + 1];
        acc += w * partO[((size_t)c * N + n) * 128 + d];
    }
    float evals = acc / L;
    if (evals != evals) evals = 0.f;   // match reference's isnan guard
    float iv = rowc[n * 4 + 2];
    out[(size_t)n * 128 + d] = (evals - x[(size_t)n * 128 + d]) * iv;
}

// ---------------------------------------------------------------- launch
extern "C" void kernel_launch(void* const* d_in, const int* in_sizes, int n_in,
                              void* d_out, int out_size, void* d_ws, size_t ws_size,
                              hipStream_t stream) {
    const float* x     = (const float*)d_in[0];
    const float* t     = (const float*)d_in[1];
    const float* train = (const float*)d_in[2];
    float* out = (float*)d_out;

    const int N = in_sizes[1];            // 4096
    const int D = 128;
    const int M = in_sizes[2] / D;        // 16384

    char* ws = (char*)d_ws;
    size_t off = 0;
    auto alloc = [&](size_t bytes) -> void* {
        void* p = ws + off;
        off = (off + bytes + 255) & ~(size_t)255;
        return p;
    };
    u16* Khi   = (u16*)alloc((size_t)M * D * 2);
    u16* Klo   = (u16*)alloc((size_t)M * D * 2);
    u16* Vt    = (u16*)alloc((size_t)M * D * 2);
    u16* Qhi   = (u16*)alloc((size_t)N * D * 2);
    u16* Qlo   = (u16*)alloc((size_t)N * D * 2);
    float* rowc = (float*)alloc((size_t)N * 16);
    float* y2   = (float*)alloc((size_t)M * 4);
    size_t base = off;
    size_t per  = (size_t)N * D * 4 + (size_t)N * 8 + 512;   // partO + partML per chunk
    int split = 16;
    while (split > 1 && base + per * split > ws_size) split >>= 1;
    float* partO  = (float*)alloc((size_t)split * N * D * 4);
    float* partML = (float*)alloc((size_t)split * N * 8);

    int nconvblk = (N * D / 4 + 255) / 256;          // 512
    int nblk = nconvblk + M / 64;                    // + 256
    prep_kernel<<<nblk, 256, 0, stream>>>(x, t, train, Qhi, Qlo, rowc,
                                          Khi, Klo, Vt, y2, N * D / 4, N, M, nconvblk);

    int mchunk = M / split;
    dim3 grid(split, N / 128);
    flash_kernel<<<grid, 512, 0, stream>>>(Khi, Klo, Vt, Qhi, Qlo, rowc, y2,
                                           partO, partML, N, M, mchunk);
    combine_kernel<<<N, 128, 0, stream>>>(partO, partML, x, rowc, out, N, split);
}

// Round 15
// 176.018 us; speedup vs baseline: 1.0325x; 1.0083x over previous
//
#include <hip/hip_runtime.h>

typedef unsigned int u32;
typedef unsigned short u16;
typedef short s16x8 __attribute__((ext_vector_type(8)));
typedef float f32x4 __attribute__((ext_vector_type(4)));

#define BETA_MIN 0.1f
#define BETA_MAX 20.0f

#define MFMA16(a, b, c) __builtin_amdgcn_mfma_f32_16x16x32_bf16(a, b, c, 0, 0, 0)

__device__ __forceinline__ u16 f2bf(float f) {
    u32 u = __float_as_uint(f);
    u32 r = u + 0x7FFFu + ((u >> 16) & 1u);   // round-to-nearest-even on bf16 boundary
    return (u16)(r >> 16);
}
__device__ __forceinline__ float bf2f(u16 h) {
    return __uint_as_float(((u32)h) << 16);
}
__device__ __forceinline__ f32x4 zero4() {
    f32x4 z = {0.f, 0.f, 0.f, 0.f};
    return z;
}

// async global->LDS 16B DMA: no VGPR round-trip. Dest = wave-uniform base + lane*16
// (LINEAR), so the bank-swizzle is applied on the per-lane GLOBAL source address and
// again on the LDS read address (both-sides-or-neither, same involution).
__device__ __forceinline__ void gload_lds16(const void* g, void* l) {
    __builtin_amdgcn_global_load_lds(
        (__attribute__((address_space(1))) void*)(void*)g,
        (__attribute__((address_space(3))) void*)l, 16, 0, 0);
}

// DPP lane-rotate within 16-lane rows; VALU-latency cross-lane (vs ds_swizzle ~100cyc)
template <int CTRL>
__device__ __forceinline__ float dppf(float x) {
    return __int_as_float(__builtin_amdgcn_update_dpp(
        0, __float_as_int(x), CTRL, 0xF, 0xF, false));
}
// reduce across the 16 contiguous lanes of a DPP row; all lanes get the result
__device__ __forceinline__ float rowmax16(float x) {
    x = fmaxf(x, dppf<0xB1>(x));    // quad_perm [1,0,3,2]  (xor 1)
    x = fmaxf(x, dppf<0x4E>(x));    // quad_perm [2,3,0,1]  (xor 2)
    x = fmaxf(x, dppf<0x124>(x));   // row_ror:4
    x = fmaxf(x, dppf<0x128>(x));   // row_ror:8
    return x;
}
__device__ __forceinline__ float rowsum16(float x) {
    x += dppf<0xB1>(x);
    x += dppf<0x4E>(x);
    x += dppf<0x124>(x);
    x += dppf<0x128>(x);
    return x;
}

// ---------------------------------------------------------------- fused prep kernel
// blocks [0, nconvblk): x -> Qhi/Qlo bf16x2 split + rowc VP-SDE constants
// blocks [nconvblk, ...): train -> Khi/Klo (row-major) + Vt (LDS-transposed) + y2
// r15 train-path rework: per lane, 1 float4 load (contiguous d=4ln..4ln+3) + 2 uint2
// packed stores (256B coalesced segments) replaces 4 stride-32 scalar loads + 8
// scalar u16 stores (64B segments). T-writes go 4-way bank-conflicted (minor phase).
__global__ __launch_bounds__(256)
void prep_kernel(const float* __restrict__ x, const float* __restrict__ t,
                 const float* __restrict__ train,
                 u16* __restrict__ Qhi, u16* __restrict__ Qlo, float* __restrict__ rowc,
                 u16* __restrict__ Khi, u16* __restrict__ Klo, u16* __restrict__ Vt,
                 float* __restrict__ y2, int total4, int N, int M, int nconvblk) {
    __shared__ u16 T[128][66];
    if ((int)blockIdx.x < nconvblk) {
        int idx = blockIdx.x * 256 + threadIdx.x;
        if (idx < N) {
            float tv   = t[idx];
            float lm   = -0.25f * tv * tv * (BETA_MAX - BETA_MIN) - 0.5f * tv * BETA_MIN;
            float mean = __expf(lm);
            float e2   = __expf(2.0f * lm);
            float s2   = fmaxf(1.0f - e2, 1e-12f);
            float iv   = 1.0f / s2;
            rowc[idx * 4 + 0] = mean * iv;
            rowc[idx * 4 + 1] = -0.5f * mean * mean * iv;
            rowc[idx * 4 + 2] = iv;
            rowc[idx * 4 + 3] = 0.f;
        }
        if (idx >= total4) return;
        float4 v = ((const float4*)x)[idx];
        float f[4] = {v.x, v.y, v.z, v.w};
        u32 hp[2], lp[2];
        u16 h[4], l[4];
#pragma unroll
        for (int j = 0; j < 4; ++j) {
            h[j] = f2bf(f[j]);
            l[j] = f2bf(f[j] - bf2f(h[j]));
        }
        hp[0] = (u32)h[0] | ((u32)h[1] << 16);
        hp[1] = (u32)h[2] | ((u32)h[3] << 16);
        lp[0] = (u32)l[0] | ((u32)l[1] << 16);
        lp[1] = (u32)l[2] | ((u32)l[3] << 16);
        ((uint2*)Qhi)[idx] = make_uint2(hp[0], hp[1]);
        ((uint2*)Qlo)[idx] = make_uint2(lp[0], lp[1]);
        return;
    }
    // ---- train prep ----
    const int tt = threadIdx.x;
    const int m0 = (blockIdx.x - nconvblk) * 64;
    const int g = tt >> 5, ln = tt & 31;
#pragma unroll
    for (int i = 0; i < 8; ++i) {
        int lr = i * 8 + g;
        int m  = m0 + lr;
        const float* row = train + (size_t)m * 128;
        float4 v = ((const float4*)row)[ln];     // d = 4ln..4ln+3; 512B coalesced
        float f[4] = {v.x, v.y, v.z, v.w};
        u16 h[4], l[4];
        float acc = 0.f;
#pragma unroll
        for (int j = 0; j < 4; ++j) {
            h[j] = f2bf(f[j]);
            l[j] = f2bf(f[j] - bf2f(h[j]));
            T[4 * ln + j][lr] = h[j];            // transpose write (4-way conflict ok)
            acc += f[j] * f[j];
        }
        ((uint2*)(Khi + (size_t)m * 128))[ln] =  // 8B/lane, 256B coalesced segment
            make_uint2((u32)h[0] | ((u32)h[1] << 16), (u32)h[2] | ((u32)h[3] << 16));
        ((uint2*)(Klo + (size_t)m * 128))[ln] =
            make_uint2((u32)l[0] | ((u32)l[1] << 16), (u32)l[2] | ((u32)l[3] << 16));
#pragma unroll
        for (int dd = 16; dd >= 1; dd >>= 1) acc += __shfl_xor(acc, dd, 32);
        if (ln == 0) y2[m] = acc;
    }
    __syncthreads();
#pragma unroll
    for (int i = 0; i < 4; ++i) {
        int c = i * 256 + tt;                    // 0..1023
        int d = c >> 3, mo = (c & 7) * 8;
        u32 w0 = *(const u32*)&T[d][mo + 0];
        u32 w1 = *(const u32*)&T[d][mo + 2];
        u32 w2 = *(const u32*)&T[d][mo + 4];
        u32 w3 = *(const u32*)&T[d][mo + 6];
        *(uint4*)(Vt + (size_t)d * M + m0 + mo) = make_uint4(w0, w1, w2, w3);
    }
}

// ---------------------------------------------------------------- flash kernel
// grid = (split, N/128); block = 512 (8 waves, 16 q-rows/wave).
// FINAL VERIFIED FORM (r8/r14: passed absmax 0.5, flash ~108-112us, VGPR 64, no
// scratch): global_load_lds double-buffer, one barrier per tile, both-sides XOR
// swizzle, XCD-locked chunks (FETCH 14.7MB), branchless f2bf softmax.
// SPILL/FRAGILITY LEDGER (r1-r13, do not reintroduce):
//  - reg-staging (r1), defer-max branch (r2/r3/r7): scratch spills 0.85-8.1 GB
//  - libm exp2f (r11): +15% VALU; raw exp2 builtin (r12): WRONG (absmax 2.9e6)
//  - cvtpk+vec-rescale in __expf build (r13): WRONG (absmax 77) -- schedule-fragile
// The softmax below is the only verified-correct codegen: branchless, scalar
// f2bf pack, in-loop scalar O-rescale, __expf. DO NOT TOUCH THIS KERNEL.
__global__ __launch_bounds__(512, 4)
void flash_kernel(const u16* __restrict__ Khi, const u16* __restrict__ Klo,
                  const u16* __restrict__ Vt,  const u16* __restrict__ Qhi,
                  const u16* __restrict__ Qlo, const float* __restrict__ rowc,
                  const float* __restrict__ y2, float* __restrict__ partO,
                  float* __restrict__ partML, int N, int M, int mchunk) {
    __shared__ u16 sK[2][2][32][128];  // [buf][hi/lo][row][d] LINEAR (DMA dest)
    __shared__ u16 sV[2][128][32];     // [buf][d][m]          LINEAR (DMA dest)
    __shared__ u16 sP[8][16][40];      // per-wave P tile (C-layout -> A-layout)

    const int tid  = threadIdx.x;
    const int wave = tid >> 6, lane = tid & 63;
    const int l15  = lane & 15, quad = lane >> 4;
    const int chunk = blockIdx.x, qb = blockIdx.y;
    const int q0 = qb * 128 + wave * 16;
    const int m_begin = chunk * mchunk;

    // staging source pointers, per-lane, chunk-XOR pre-swizzled to match the reads
    const int kr = tid >> 4;                    // K row 0..31
    const int kc = (tid & 15) ^ (kr & 7);       // source 16B-chunk (involution)
    const int vd = tid >> 2;                    // V d-row 0..127
    const int vc = (tid & 3) ^ ((vd >> 1) & 3);
    const u16* gKh = Khi + (size_t)(m_begin + kr) * 128 + kc * 8;
    const u16* gKl = Klo + (size_t)(m_begin + kr) * 128 + kc * 8;
    const u16* gV  = Vt  + (size_t)vd * M + m_begin + vc * 8;
    const int wb = wave * 1024;                 // wave-uniform byte offset per plane

    // LDS read byte-offsets (hoisted; same XOR as the staged source)
    int aK[4];
#pragma unroll
    for (int kb = 0; kb < 4; ++kb)
        aK[kb] = l15 * 256 + ((((kb * 4 + quad) ^ (l15 & 7))) << 4);
    const int aV = l15 * 64 + ((quad ^ ((l15 >> 1) & 3)) << 4);

    // Q fragments in registers: A-layout A[m=l15][k=quad*8+j]
    s16x8 qh[4], ql[4];
    {
        int row = q0 + l15;
        const u16* ph = Qhi + (size_t)row * 128;
        const u16* pl = Qlo + (size_t)row * 128;
#pragma unroll
        for (int kb = 0; kb < 4; ++kb) {
            qh[kb] = *(const s16x8*)(ph + kb * 32 + quad * 8);
            ql[kb] = *(const s16x8*)(pl + kb * 32 + quad * 8);
        }
    }
    float av[4], bv[4];
#pragma unroll
    for (int k = 0; k < 4; ++k) {
        int r = q0 + quad * 4 + k;
        av[k] = rowc[r * 4 + 0];
        bv[k] = rowc[r * 4 + 1];
    }

    f32x4 O[8];
#pragma unroll
    for (int db = 0; db < 8; ++db) O[db] = zero4();
    float m_run[4], l_run[4];
#pragma unroll
    for (int k = 0; k < 4; ++k) { m_run[k] = -INFINITY; l_run[k] = 0.f; }

    // stage(buf): 3 async 16B DMAs per thread, zero data VGPRs; advances sources
    auto stage = [&](int buf) {
        gload_lds16(gKh, (char*)&sK[buf][0][0][0] + wb);
        gload_lds16(gKl, (char*)&sK[buf][1][0][0] + wb);
        gload_lds16(gV,  (char*)&sV[buf][0][0]    + wb);
        gKh += 32 * 128; gKl += 32 * 128; gV += 32;
    };

    stage(0);
    __syncthreads();                    // implicit vmcnt(0) drain: tile 0 ready
    int cur = 0;

    for (int mt = 0; mt < mchunk; mt += 32) {
        if (mt + 32 < mchunk) stage(cur ^ 1);   // async: lands by next barrier
        const int m0 = m_begin + mt;
        float y2v0 = y2[m0 + l15];
        float y2v1 = y2[m0 + 16 + l15];

        const char* Kb = (const char*)&sK[cur][0][0][0];
        const char* Vb = (const char*)&sV[cur][0][0];

        // S GEMM: bf16x3
        f32x4 S[2];
        S[0] = zero4(); S[1] = zero4();
        __builtin_amdgcn_s_setprio(1);
#pragma unroll
        for (int kb = 0; kb < 4; ++kb) {
            s16x8 bh0 = *(const s16x8*)(Kb + aK[kb]);           // hi, rows l15
            s16x8 bh1 = *(const s16x8*)(Kb + aK[kb] + 4096);    // hi, rows 16+l15
            s16x8 bl0 = *(const s16x8*)(Kb + aK[kb] + 8192);    // lo, rows l15
            s16x8 bl1 = *(const s16x8*)(Kb + aK[kb] + 12288);   // lo, rows 16+l15
            S[0] = MFMA16(qh[kb], bh0, S[0]);
            S[0] = MFMA16(ql[kb], bh0, S[0]);
            S[0] = MFMA16(qh[kb], bl0, S[0]);
            S[1] = MFMA16(qh[kb], bh1, S[1]);
            S[1] = MFMA16(ql[kb], bh1, S[1]);
            S[1] = MFMA16(qh[kb], bl1, S[1]);
        }
        __builtin_amdgcn_s_setprio(0);

        // online softmax (BRANCHLESS -- see ledger above); C-layout:
        // row q = quad*4+k (16 contiguous lanes = one DPP row)
#pragma unroll
        for (int k = 0; k < 4; ++k) {
            float s0 = av[k] * S[0][k] + bv[k] * y2v0;
            float s1 = av[k] * S[1][k] + bv[k] * y2v1;
            float rm    = rowmax16(fmaxf(s0, s1));
            float mnew  = fmaxf(m_run[k], rm);
            float alpha = __expf(m_run[k] - mnew);   // exp(-inf)=0 on first tile
            float p0 = __expf(s0 - mnew);
            float p1 = __expf(s1 - mnew);
            m_run[k] = mnew;
            // deferred row-sum: per-lane partial; alpha is row-uniform so this is exact
            l_run[k] = l_run[k] * alpha + (p0 + p1);
            sP[wave][quad * 4 + k][l15]      = f2bf(p0);
            sP[wave][quad * 4 + k][16 + l15] = f2bf(p1);
#pragma unroll
            for (int db = 0; db < 8; ++db) O[db][k] *= alpha;
        }
        // same-wave LDS write->read ordering (per-wave sP region; lgkm only --
        // does NOT stall on the outstanding global_load_lds DMAs, which are vmcnt)
        asm volatile("s_waitcnt lgkmcnt(0)" ::: "memory");

        // PV: A = P (A-layout), B = Vt (B[k=m][n=d])
        s16x8 pa = *(const s16x8*)&sP[wave][l15][quad * 8];
        __builtin_amdgcn_s_setprio(1);
#pragma unroll
        for (int db = 0; db < 8; ++db) {
            s16x8 vb = *(const s16x8*)(Vb + db * 1024 + aV);
            O[db] = MFMA16(pa, vb, O[db]);
        }
        __builtin_amdgcn_s_setprio(0);
        __syncthreads();   // drains vmcnt: next tile's DMAs landed; all reads done
        cur ^= 1;
    }

    // epilogue: unnormalized O + (m, l) partials
#pragma unroll
    for (int db = 0; db < 8; ++db) {
#pragma unroll
        for (int k = 0; k < 4; ++k) {
            int row = q0 + quad * 4 + k;
            partO[((size_t)chunk * N + row) * 128 + db * 16 + l15] = O[db][k];
        }
    }
#pragma unroll
    for (int k = 0; k < 4; ++k) {
        float lsum = rowsum16(l_run[k]);
        if (l15 == 0) {
            int row = q0 + quad * 4 + k;
            partML[((size_t)chunk * N + row) * 2 + 0] = m_run[k];
            partML[((size_t)chunk * N + row) * 2 + 1] = lsum;
        }
    }
}

// ---------------------------------------------------------------- combine
__global__ void combine_kernel(const float* __restrict__ partO, const float* __restrict__ partML,
                               const float* __restrict__ x, const float* __restrict__ rowc,
                               float* __restrict__ out, int N, int split) {
    int n = blockIdx.x, d = threadIdx.x;
    float Mx = -INFINITY;
    for (int c = 0; c < split; ++c)
        Mx = fmaxf(Mx, partML[((size_t)c * N + n) * 2]);
    float L = 0.f, acc = 0.f;
    for (int c = 0; c < split; ++c) {
        float w = __expf(partML[((size_t)c * N + n) * 2] - Mx);
        L   += w * partML[((size_t)c * N + n) * 2 + 1];
        acc += w * partO[((size_t)c * N + n) * 128 + d];
    }
    float evals = acc / L;
    if (evals != evals) evals = 0.f;   // match reference's isnan guard
    float iv = rowc[n * 4 + 2];
    out[(size_t)n * 128 + d] = (evals - x[(size_t)n * 128 + d]) * iv;
}

// ---------------------------------------------------------------- launch
extern "C" void kernel_launch(void* const* d_in, const int* in_sizes, int n_in,
                              void* d_out, int out_size, void* d_ws, size_t ws_size,
                              hipStream_t stream) {
    const float* x     = (const float*)d_in[0];
    const float* t     = (const float*)d_in[1];
    const float* train = (const float*)d_in[2];
    float* out = (float*)d_out;

    const int N = in_sizes[1];            // 4096
    const int D = 128;
    const int M = in_sizes[2] / D;        // 16384

    char* ws = (char*)d_ws;
    size_t off = 0;
    auto alloc = [&](size_t bytes) -> void* {
        void* p = ws + off;
        off = (off + bytes + 255) & ~(size_t)255;
        return p;
    };
    u16* Khi   = (u16*)alloc((size_t)M * D * 2);
    u16* Klo   = (u16*)alloc((size_t)M * D * 2);
    u16* Vt    = (u16*)alloc((size_t)M * D * 2);
    u16* Qhi   = (u16*)alloc((size_t)N * D * 2);
    u16* Qlo   = (u16*)alloc((size_t)N * D * 2);
    float* rowc = (float*)alloc((size_t)N * 16);
    float* y2   = (float*)alloc((size_t)M * 4);
    size_t base = off;
    size_t per  = (size_t)N * D * 4 + (size_t)N * 8 + 512;   // partO + partML per chunk
    int split = 16;
    while (split > 1 && base + per * split > ws_size) split >>= 1;
    float* partO  = (float*)alloc((size_t)split * N * D * 4);
    float* partML = (float*)alloc((size_t)split * N * 8);

    int nconvblk = (N * D / 4 + 255) / 256;          // 512
    int nblk = nconvblk + M / 64;                    // + 256
    prep_kernel<<<nblk, 256, 0, stream>>>(x, t, train, Qhi, Qlo, rowc,
                                          Khi, Klo, Vt, y2, N * D / 4, N, M, nconvblk);

    int mchunk = M / split;
    dim3 grid(split, N / 128);
    flash_kernel<<<grid, 512, 0, stream>>>(Khi, Klo, Vt, Qhi, Qlo, rowc, y2,
                                           partO, partML, N, M, mchunk);
    combine_kernel<<<N, 128, 0, stream>>>(partO, partML, x, rowc, out, N, split);
}